// Round 5
// baseline (265.662 us; speedup 1.0000x reference)
//
#include <hip/hip_runtime.h>

#define HW 4096
#define BN_RS 0.9999950000374998f   // 1/sqrt(1+1e-5)

typedef __attribute__((ext_vector_type(8))) short  short8;
typedef __attribute__((ext_vector_type(8))) unsigned short ushort8;
typedef __attribute__((ext_vector_type(4))) float  f32x4;

__device__ __forceinline__ float silu_f(float v) { return v / (1.0f + __expf(-v)); }
__device__ __forceinline__ int clamp64(int v) { return v < 0 ? 0 : (v > 63 ? 63 : v); }
__device__ __forceinline__ unsigned short f2bf(float f) {
    union { float f; unsigned u; } v; v.f = f;
    unsigned r = v.u + 0x7fff + ((v.u >> 16) & 1);   // RNE
    return (unsigned short)(r >> 16);
}

// ---------------- 1x1 conv + BN + SiLU, bf16 MFMA GEMM ----------------
// Block: 64co x 64pos tile, 4 waves as 2x2 of 32x32, BK=32.
// SE=true additionally accumulates sum over pos into sbuf[b*CO+co] (atomic).
template<int CO, int CIN, bool SE>
__global__ __launch_bounds__(256) void k_conv1x1_mfma(
    const float* __restrict__ X, const float* __restrict__ Wt,
    const float* __restrict__ gg, const float* __restrict__ bb,
    float* __restrict__ Y, float* __restrict__ sbuf)
{
    const int b  = blockIdx.z;
    const int p0 = blockIdx.x * 64;
    const int c0 = blockIdx.y * 64;
    const int tid  = threadIdx.x;
    const int wave = tid >> 6, lane = tid & 63;
    const int wm = wave >> 1, wn = wave & 1;
    const int lrow = lane & 15, lkg = lane >> 4;

    __shared__ __align__(16) unsigned short As[64 * 40];  // [co][k]
    __shared__ __align__(16) unsigned short Bs[64 * 40];  // [pos][k], k-group XOR swizzle

    const float* Xb = X + (size_t)b * CIN * HW;

    f32x4 acc[2][2];
    #pragma unroll
    for (int i = 0; i < 2; ++i)
        #pragma unroll
        for (int j = 0; j < 2; ++j) acc[i][j] = (f32x4){0.f, 0.f, 0.f, 0.f};

    const int arow = tid >> 2, akc = (tid & 3) * 8;

    for (int k0 = 0; k0 < CIN; k0 += 32) {
        __syncthreads();
        {
            const float* wp = &Wt[(size_t)(c0 + arow) * CIN + k0 + akc];
            float4 v0 = *(const float4*)wp;
            float4 v1 = *(const float4*)(wp + 4);
            ushort8 u;
            u[0] = f2bf(v0.x); u[1] = f2bf(v0.y); u[2] = f2bf(v0.z); u[3] = f2bf(v0.w);
            u[4] = f2bf(v1.x); u[5] = f2bf(v1.y); u[6] = f2bf(v1.z); u[7] = f2bf(v1.w);
            *(ushort8*)&As[arow * 40 + akc] = u;
        }
        #pragma unroll
        for (int it = 0; it < 2; ++it) {
            int i  = tid + it * 256;          // 0..511
            int kk = i >> 4;                  // 0..31
            int p4 = (i & 15) * 4;
            float4 v = *(const float4*)&Xb[(size_t)(k0 + kk) * HW + p0 + p4];
            int kg = kk >> 3, kl = kk & 7;
            float vv[4] = {v.x, v.y, v.z, v.w};
            #pragma unroll
            for (int jj = 0; jj < 4; ++jj) {
                int pos = p4 + jj;
                int kgs = kg ^ ((pos >> 2) & 3);
                Bs[pos * 40 + kgs * 8 + kl] = f2bf(vv[jj]);
            }
        }
        __syncthreads();

        short8 aF[2], bF[2];
        #pragma unroll
        for (int mi = 0; mi < 2; ++mi)
            aF[mi] = *(const short8*)&As[(wm * 32 + mi * 16 + lrow) * 40 + lkg * 8];
        #pragma unroll
        for (int ni = 0; ni < 2; ++ni) {
            int pos = wn * 32 + ni * 16 + lrow;
            int kgs = lkg ^ ((pos >> 2) & 3);
            bF[ni] = *(const short8*)&Bs[pos * 40 + kgs * 8];
        }
        #pragma unroll
        for (int mi = 0; mi < 2; ++mi)
            #pragma unroll
            for (int ni = 0; ni < 2; ++ni)
                acc[mi][ni] = __builtin_amdgcn_mfma_f32_16x16x32_bf16(
                    aF[mi], bF[ni], acc[mi][ni], 0, 0, 0);
    }

    // epilogue: D row = (lane>>4)*4 + reg, col = lane&15
    #pragma unroll
    for (int mi = 0; mi < 2; ++mi) {
        #pragma unroll
        for (int r = 0; r < 4; ++r) {
            int co = c0 + wm * 32 + mi * 16 + lkg * 4 + r;
            float s  = gg[co] * BN_RS;
            float bi = bb[co];
            float v0 = silu_f(fmaf(acc[mi][0][r], s, bi));
            float v1 = silu_f(fmaf(acc[mi][1][r], s, bi));
            size_t rowb = ((size_t)b * CO + co) * HW + p0 + wn * 32 + lrow;
            Y[rowb]      = v0;
            Y[rowb + 16] = v1;
            if (SE) {
                float vs = v0 + v1;
                vs += __shfl_xor(vs, 1);
                vs += __shfl_xor(vs, 2);
                vs += __shfl_xor(vs, 4);
                vs += __shfl_xor(vs, 8);
                if (lrow == 0) atomicAdd(&sbuf[b * CO + co], vs);
            }
        }
    }
}

// -------- 3x3 conv (256 -> 18), pad 1, channel-split partial sums --------
__global__ __launch_bounds__(256) void k_conv_off(
    const float* __restrict__ Hh, const float* __restrict__ Wo,
    float* __restrict__ OffP)
{
    const int y = blockIdx.x;
    const int b = blockIdx.y;
    const int q = blockIdx.z;
    const int tid = threadIdx.x;
    const int x = tid & 63;
    const int g = tid >> 6;

    __shared__ __align__(16) float hs[3][32][66];
    __shared__ __align__(16) float ws[18][32][12];

    if (tid < 96) {
        int r = tid >> 5, ci = tid & 31;
        hs[r][ci][0] = 0.f; hs[r][ci][65] = 0.f;
    }

    float acc[5] = {0.f, 0.f, 0.f, 0.f, 0.f};
    const float* Hb = Hh + (size_t)b * 256 * HW;

    for (int cc = 0; cc < 2; ++cc) {
        const int c0 = q * 64 + cc * 32;
        __syncthreads();
        for (int i = tid; i < 5184; i += 256) {
            int co = i / 288, r = i % 288;
            int ci = r / 9, t = r - ci * 9;
            ws[co][ci][t] = Wo[(size_t)co * 2304 + (size_t)(c0 + ci) * 9 + t];
        }
        #pragma unroll
        for (int it = 0; it < 6; ++it) {
            int i   = tid + it * 256;
            int r   = i >> 9;
            int rem = i & 511;
            int ci  = rem >> 4;
            int x4  = (rem & 15) << 2;
            int yy  = y + r - 1;
            float4 v = make_float4(0.f, 0.f, 0.f, 0.f);
            if ((unsigned)yy < 64u)
                v = *(const float4*)&Hb[(size_t)(c0 + ci) * HW + yy * 64 + x4];
            hs[r][ci][1 + x4] = v.x;
            hs[r][ci][2 + x4] = v.y;
            hs[r][ci][3 + x4] = v.z;
            hs[r][ci][4 + x4] = v.w;
        }
        __syncthreads();
        #pragma unroll 2
        for (int ci = 0; ci < 32; ++ci) {
            float v[9];
            #pragma unroll
            for (int r = 0; r < 3; ++r) {
                v[r * 3 + 0] = hs[r][ci][x];
                v[r * 3 + 1] = hs[r][ci][x + 1];
                v[r * 3 + 2] = hs[r][ci][x + 2];
            }
            #pragma unroll
            for (int j = 0; j < 5; ++j) {
                int co = g + (j << 2);
                if (co < 18) {
                    const float4 w0 = *(const float4*)&ws[co][ci][0];
                    const float4 w1 = *(const float4*)&ws[co][ci][4];
                    const float  w8 = ws[co][ci][8];
                    float a = acc[j];
                    a = fmaf(w0.x, v[0], a); a = fmaf(w0.y, v[1], a);
                    a = fmaf(w0.z, v[2], a); a = fmaf(w0.w, v[3], a);
                    a = fmaf(w1.x, v[4], a); a = fmaf(w1.y, v[5], a);
                    a = fmaf(w1.z, v[6], a); a = fmaf(w1.w, v[7], a);
                    a = fmaf(w8,   v[8], a);
                    acc[j] = a;
                }
            }
        }
    }
    #pragma unroll
    for (int j = 0; j < 5; ++j) {
        int co = g + (j << 2);
        if (co < 18)
            OffP[(((size_t)q * 4 + b) * 18 + co) * HW + y * 64 + x] = acc[j];
    }
}

// -------- combine 4 channel-split partials + bias -> final offsets --------
__global__ __launch_bounds__(256) void k_off_combine(
    const float* __restrict__ OffP, const float* __restrict__ Bo,
    float* __restrict__ Off)
{
    const int bt = blockIdx.x;         // b*18 + t, 72 blocks
    const int b = bt / 18, t = bt - b * 18;
    const float bias = Bo[t];
    const size_t plane = ((size_t)b * 18 + t) * HW;
    #pragma unroll
    for (int it = 0; it < 4; ++it) {
        int p4 = (threadIdx.x + it * 256) * 4;
        float4 s = *(const float4*)&OffP[plane + p4];
        #pragma unroll
        for (int q = 1; q < 4; ++q) {
            float4 v = *(const float4*)&OffP[((size_t)q * 4 * 18) * HW + plane + p4];
            s.x += v.x; s.y += v.y; s.z += v.z; s.w += v.w;
        }
        s.x += bias; s.y += bias; s.z += bias; s.w += bias;
        *(float4*)&Off[plane + p4] = s;
    }
}

// ------------- deformable depthwise 3x3 + BN + SiLU + residual -------------
// grid (y=64, b=4, q=8). k-outer / 8-channels-inner to keep VGPR low;
// dw-weights + BN params staged in LDS (wave-uniform reads = broadcast).
__global__ __launch_bounds__(256, 6) void k_deform(
    const float* __restrict__ Hh, const float* __restrict__ Off,
    const float* __restrict__ Wd, const float* __restrict__ Gb,
    const float* __restrict__ Bb, float* __restrict__ H2)
{
    const int y = blockIdx.x;
    const int b = blockIdx.y;
    const int q = blockIdx.z;
    const int tid = threadIdx.x;
    const int x = tid & 63;
    const int g = tid >> 6;
    const int pos = y * 64 + x;

    __shared__ __align__(16) float wds[9 * 32];   // [k][lc]
    __shared__ float gbs[32], bbs[32];

    // 288 entries, 256 threads: strided loop (R4 bug: tid<288 covered all threads)
    for (int i = tid; i < 288; i += 256) {
        int lc = i & 31, k = i >> 5;
        wds[i] = Wd[(q * 32 + lc) * 9 + k];
    }
    if (tid < 32) {
        gbs[tid] = Gb[q * 32 + tid] * BN_RS;
        bbs[tid] = Bb[q * 32 + tid];
    }
    __syncthreads();

    float acc[8];
    #pragma unroll
    for (int j = 0; j < 8; ++j) acc[j] = 0.f;

    const float* Ob  = Off + (size_t)b * 18 * HW + pos;
    const float* hb0 = Hh + ((size_t)(b * 256 + q * 32 + g * 8) << 12);

    for (int k = 0; k < 9; ++k) {
        float dy = Ob[(size_t)(2 * k) * HW];
        float dx = Ob[(size_t)(2 * k + 1) * HW];
        float py = (float)(y + k / 3 - 1) + dy;
        float px = (float)(x + k % 3 - 1) + dx;
        float fy0 = floorf(py), fx0 = floorf(px);
        int y0 = (int)fy0, x0 = (int)fx0;
        float fy = py - fy0, fx = px - fx0;
        int y1 = y0 + 1, x1 = x0 + 1;
        float gy0 = 1.0f - fy, gx0 = 1.0f - fx;
        bool vy0 = ((unsigned)y0 < 64u), vy1 = ((unsigned)y1 < 64u);
        bool vx0 = ((unsigned)x0 < 64u), vx1 = ((unsigned)x1 < 64u);
        int cy0 = clamp64(y0), cy1 = clamp64(y1);
        int cx0 = clamp64(x0), cx1 = clamp64(x1);
        int i00 = cy0 * 64 + cx0, i01 = cy0 * 64 + cx1;
        int i10 = cy1 * 64 + cx0, i11 = cy1 * 64 + cx1;
        float w00 = (vy0 && vx0) ? gy0 * gx0 : 0.0f;
        float w01 = (vy0 && vx1) ? gy0 * fx  : 0.0f;
        float w10 = (vy1 && vx0) ? fy  * gx0 : 0.0f;
        float w11 = (vy1 && vx1) ? fy  * fx  : 0.0f;

        float4 wka = *(const float4*)&wds[k * 32 + g * 8];
        float4 wkb = *(const float4*)&wds[k * 32 + g * 8 + 4];
        float wk[8] = {wka.x, wka.y, wka.z, wka.w, wkb.x, wkb.y, wkb.z, wkb.w};

        #pragma unroll
        for (int j = 0; j < 8; ++j) {
            const float* hb = hb0 + ((size_t)j << 12);
            float val = hb[i00] * w00 + hb[i01] * w01
                      + hb[i10] * w10 + hb[i11] * w11;
            acc[j] = fmaf(val, wk[j], acc[j]);
        }
    }

    #pragma unroll
    for (int j = 0; j < 8; ++j) {
        int lc = g * 8 + j;
        const float* hb = hb0 + ((size_t)j << 12);
        float t = fmaf(acc[j], gbs[lc], bbs[lc]);
        H2[((size_t)(b * 256 + q * 32 + lc) << 12) + pos] = silu_f(t) + hb[pos];
    }
}

// ---------------- SE: fc1(silu) + fc2(sigmoid) ----------------
// sb holds SUMS over HxW (from conv2 epilogue atomics); scale by 1/4096 here.
__global__ __launch_bounds__(256) void k_se_fc(
    const float* __restrict__ sb, const float* __restrict__ wf1,
    const float* __restrict__ bf1, const float* __restrict__ wf2,
    const float* __restrict__ bf2, float* __restrict__ s2)
{
    const int b = blockIdx.x;
    const int t = threadIdx.x;
    __shared__ float sv[512];
    __shared__ float s1[32];
    sv[t]       = sb[b * 512 + t] * (1.0f / 4096.0f);
    sv[t + 256] = sb[b * 512 + t + 256] * (1.0f / 4096.0f);
    __syncthreads();
    if (t < 32) {
        float a = bf1[t];
        const float* w = wf1 + t * 512;
        for (int i = 0; i < 512; ++i) a = fmaf(w[i], sv[i], a);
        s1[t] = silu_f(a);
    }
    __syncthreads();
    #pragma unroll
    for (int it = 0; it < 2; ++it) {
        int co = t + it * 256;
        float a = bf2[co];
        const float* w = wf2 + co * 32;
        #pragma unroll
        for (int i = 0; i < 32; ++i) a = fmaf(w[i], s1[i], a);
        s2[b * 512 + co] = 1.0f / (1.0f + __expf(-a));
    }
}

// ---------------- final: out *= s ----------------
__global__ __launch_bounds__(256) void k_se_scale(
    float* __restrict__ Y, const float* __restrict__ s2)
{
    size_t i = (size_t)blockIdx.x * 256 + threadIdx.x;
    int bc = (int)(i >> 10);
    float sc = s2[bc];
    float4 v = ((float4*)Y)[i];
    v.x *= sc; v.y *= sc; v.z *= sc; v.w *= sc;
    ((float4*)Y)[i] = v;
}

extern "C" void kernel_launch(void* const* d_in, const int* in_sizes, int n_in,
                              void* d_out, int out_size, void* d_ws, size_t ws_size,
                              hipStream_t stream)
{
    const float* x   = (const float*)d_in[0];
    const float* w1  = (const float*)d_in[1];
    const float* g1  = (const float*)d_in[2];
    const float* b1  = (const float*)d_in[3];
    const float* wof = (const float*)d_in[4];
    const float* bof = (const float*)d_in[5];
    const float* wdw = (const float*)d_in[6];
    const float* gb  = (const float*)d_in[7];
    const float* bbv = (const float*)d_in[8];
    const float* w2  = (const float*)d_in[9];
    const float* g2  = (const float*)d_in[10];
    const float* b2  = (const float*)d_in[11];
    const float* wf1 = (const float*)d_in[12];
    const float* bf1 = (const float*)d_in[13];
    const float* wf2 = (const float*)d_in[14];
    const float* bf2 = (const float*)d_in[15];
    float* out = (float*)d_out;

    const size_t n_h    = 4ull * 256 * HW;        // 4,194,304
    const size_t n_offp = 4ull * 4 * 18 * HW;     // 1,179,648
    const size_t n_off  = 4ull * 18 * HW;         //   294,912
    float* ws = (float*)d_ws;
    float *h, *offp, *offc, *h2, *sb, *s2;
    size_t need = (2 * n_h + n_offp + n_off + 4096) * sizeof(float);
    if (ws_size >= need) {
        h = ws; offp = h + n_h; offc = offp + n_offp; h2 = offc + n_off;
        sb = h2 + n_h; s2 = sb + 2048;
    } else {
        h = out;  // dead before conv2 writes out
        offp = ws; offc = offp + n_offp; h2 = offc + n_off;
        sb = h2 + n_h; s2 = sb + 2048;
    }

    k_conv1x1_mfma<256, 512, false><<<dim3(64, 4, 4), 256, 0, stream>>>(x, w1, g1, b1, h, nullptr);
    k_conv_off<<<dim3(64, 4, 4), 256, 0, stream>>>(h, wof, offp);
    k_off_combine<<<72, 256, 0, stream>>>(offp, bof, offc);
    k_deform<<<dim3(64, 4, 8), 256, 0, stream>>>(h, offc, wdw, gb, bbv, h2);
    hipMemsetAsync(sb, 0, 2048 * sizeof(float), stream);
    k_conv1x1_mfma<512, 256, true><<<dim3(64, 8, 4), 256, 0, stream>>>(h2, w2, g2, b2, out, sb);
    k_se_fc<<<4, 256, 0, stream>>>(sb, wf1, bf1, wf2, bf2, s2);
    k_se_scale<<<8192, 256, 0, stream>>>(out, s2);
}

// Round 6
// 236.342 us; speedup vs baseline: 1.1241x; 1.1241x over previous
//
#include <hip/hip_runtime.h>

#define HW 4096
#define BN_RS 0.9999950000374998f   // 1/sqrt(1+1e-5)

typedef __attribute__((ext_vector_type(8))) short  short8;
typedef __attribute__((ext_vector_type(8))) unsigned short ushort8;
typedef __attribute__((ext_vector_type(4))) float  f32x4;

__device__ __forceinline__ float silu_f(float v) { return v / (1.0f + __expf(-v)); }
__device__ __forceinline__ int clamp64(int v) { return v < 0 ? 0 : (v > 63 ? 63 : v); }
__device__ __forceinline__ unsigned short f2bf(float f) {
    union { float f; unsigned u; } v; v.f = f;
    unsigned r = v.u + 0x7fff + ((v.u >> 16) & 1);   // RNE
    return (unsigned short)(r >> 16);
}

// ---------------- 1x1 conv + BN + SiLU, bf16 MFMA GEMM ----------------
// Block: 64co x 64pos tile, 4 waves as 2x2 of 32x32, BK=32.
template<int CO, int CIN>
__global__ __launch_bounds__(256) void k_conv1x1_mfma(
    const float* __restrict__ X, const float* __restrict__ Wt,
    const float* __restrict__ gg, const float* __restrict__ bb,
    float* __restrict__ Y)
{
    const int b  = blockIdx.z;
    const int p0 = blockIdx.x * 64;
    const int c0 = blockIdx.y * 64;
    const int tid  = threadIdx.x;
    const int wave = tid >> 6, lane = tid & 63;
    const int wm = wave >> 1, wn = wave & 1;
    const int lrow = lane & 15, lkg = lane >> 4;

    __shared__ __align__(16) unsigned short As[64 * 40];  // [co][k]
    __shared__ __align__(16) unsigned short Bs[64 * 40];  // [pos][k], k-group XOR swizzle

    const float* Xb = X + (size_t)b * CIN * HW;

    f32x4 acc[2][2];
    #pragma unroll
    for (int i = 0; i < 2; ++i)
        #pragma unroll
        for (int j = 0; j < 2; ++j) acc[i][j] = (f32x4){0.f, 0.f, 0.f, 0.f};

    const int arow = tid >> 2, akc = (tid & 3) * 8;

    for (int k0 = 0; k0 < CIN; k0 += 32) {
        __syncthreads();
        {
            const float* wp = &Wt[(size_t)(c0 + arow) * CIN + k0 + akc];
            float4 v0 = *(const float4*)wp;
            float4 v1 = *(const float4*)(wp + 4);
            ushort8 u;
            u[0] = f2bf(v0.x); u[1] = f2bf(v0.y); u[2] = f2bf(v0.z); u[3] = f2bf(v0.w);
            u[4] = f2bf(v1.x); u[5] = f2bf(v1.y); u[6] = f2bf(v1.z); u[7] = f2bf(v1.w);
            *(ushort8*)&As[arow * 40 + akc] = u;
        }
        #pragma unroll
        for (int it = 0; it < 2; ++it) {
            int i  = tid + it * 256;          // 0..511
            int kk = i >> 4;                  // 0..31
            int p4 = (i & 15) * 4;
            float4 v = *(const float4*)&Xb[(size_t)(k0 + kk) * HW + p0 + p4];
            int kg = kk >> 3, kl = kk & 7;
            float vv[4] = {v.x, v.y, v.z, v.w};
            #pragma unroll
            for (int jj = 0; jj < 4; ++jj) {
                int pos = p4 + jj;
                int kgs = kg ^ ((pos >> 2) & 3);
                Bs[pos * 40 + kgs * 8 + kl] = f2bf(vv[jj]);
            }
        }
        __syncthreads();

        short8 aF[2], bF[2];
        #pragma unroll
        for (int mi = 0; mi < 2; ++mi)
            aF[mi] = *(const short8*)&As[(wm * 32 + mi * 16 + lrow) * 40 + lkg * 8];
        #pragma unroll
        for (int ni = 0; ni < 2; ++ni) {
            int pos = wn * 32 + ni * 16 + lrow;
            int kgs = lkg ^ ((pos >> 2) & 3);
            bF[ni] = *(const short8*)&Bs[pos * 40 + kgs * 8];
        }
        #pragma unroll
        for (int mi = 0; mi < 2; ++mi)
            #pragma unroll
            for (int ni = 0; ni < 2; ++ni)
                acc[mi][ni] = __builtin_amdgcn_mfma_f32_16x16x32_bf16(
                    aF[mi], bF[ni], acc[mi][ni], 0, 0, 0);
    }

    // epilogue: D row = (lane>>4)*4 + reg, col = lane&15
    #pragma unroll
    for (int mi = 0; mi < 2; ++mi) {
        #pragma unroll
        for (int r = 0; r < 4; ++r) {
            int co = c0 + wm * 32 + mi * 16 + lkg * 4 + r;
            float s  = gg[co] * BN_RS;
            float bi = bb[co];
            size_t rowb = ((size_t)b * CO + co) * HW + p0 + wn * 32 + lrow;
            Y[rowb]      = silu_f(fmaf(acc[mi][0][r], s, bi));
            Y[rowb + 16] = silu_f(fmaf(acc[mi][1][r], s, bi));
        }
    }
}

// -------- 3x3 conv (256 -> 18), pad 1, channel-split partial sums --------
__global__ __launch_bounds__(256) void k_conv_off(
    const float* __restrict__ Hh, const float* __restrict__ Wo,
    float* __restrict__ OffP)
{
    const int y = blockIdx.x;
    const int b = blockIdx.y;
    const int q = blockIdx.z;
    const int tid = threadIdx.x;
    const int x = tid & 63;
    const int g = tid >> 6;

    __shared__ __align__(16) float hs[3][32][66];
    __shared__ __align__(16) float ws[18][32][12];

    if (tid < 96) {
        int r = tid >> 5, ci = tid & 31;
        hs[r][ci][0] = 0.f; hs[r][ci][65] = 0.f;
    }

    float acc[5] = {0.f, 0.f, 0.f, 0.f, 0.f};
    const float* Hb = Hh + (size_t)b * 256 * HW;

    for (int cc = 0; cc < 2; ++cc) {
        const int c0 = q * 64 + cc * 32;
        __syncthreads();
        for (int i = tid; i < 5184; i += 256) {
            int co = i / 288, r = i % 288;
            int ci = r / 9, t = r - ci * 9;
            ws[co][ci][t] = Wo[(size_t)co * 2304 + (size_t)(c0 + ci) * 9 + t];
        }
        #pragma unroll
        for (int it = 0; it < 6; ++it) {
            int i   = tid + it * 256;
            int r   = i >> 9;
            int rem = i & 511;
            int ci  = rem >> 4;
            int x4  = (rem & 15) << 2;
            int yy  = y + r - 1;
            float4 v = make_float4(0.f, 0.f, 0.f, 0.f);
            if ((unsigned)yy < 64u)
                v = *(const float4*)&Hb[(size_t)(c0 + ci) * HW + yy * 64 + x4];
            hs[r][ci][1 + x4] = v.x;
            hs[r][ci][2 + x4] = v.y;
            hs[r][ci][3 + x4] = v.z;
            hs[r][ci][4 + x4] = v.w;
        }
        __syncthreads();
        #pragma unroll 2
        for (int ci = 0; ci < 32; ++ci) {
            float v[9];
            #pragma unroll
            for (int r = 0; r < 3; ++r) {
                v[r * 3 + 0] = hs[r][ci][x];
                v[r * 3 + 1] = hs[r][ci][x + 1];
                v[r * 3 + 2] = hs[r][ci][x + 2];
            }
            #pragma unroll
            for (int j = 0; j < 5; ++j) {
                int co = g + (j << 2);
                if (co < 18) {
                    const float4 w0 = *(const float4*)&ws[co][ci][0];
                    const float4 w1 = *(const float4*)&ws[co][ci][4];
                    const float  w8 = ws[co][ci][8];
                    float a = acc[j];
                    a = fmaf(w0.x, v[0], a); a = fmaf(w0.y, v[1], a);
                    a = fmaf(w0.z, v[2], a); a = fmaf(w0.w, v[3], a);
                    a = fmaf(w1.x, v[4], a); a = fmaf(w1.y, v[5], a);
                    a = fmaf(w1.z, v[6], a); a = fmaf(w1.w, v[7], a);
                    a = fmaf(w8,   v[8], a);
                    acc[j] = a;
                }
            }
        }
    }
    #pragma unroll
    for (int j = 0; j < 5; ++j) {
        int co = g + (j << 2);
        if (co < 18)
            OffP[(((size_t)q * 4 + b) * 18 + co) * HW + y * 64 + x] = acc[j];
    }
}

// -------- combine 4 channel-split partials + bias -> final offsets --------
__global__ __launch_bounds__(256) void k_off_combine(
    const float* __restrict__ OffP, const float* __restrict__ Bo,
    float* __restrict__ Off)
{
    const int bt = blockIdx.x;         // b*18 + t, 72 blocks
    const int b = bt / 18, t = bt - b * 18;
    const float bias = Bo[t];
    const size_t plane = ((size_t)b * 18 + t) * HW;
    #pragma unroll
    for (int it = 0; it < 4; ++it) {
        int p4 = (threadIdx.x + it * 256) * 4;
        float4 s = *(const float4*)&OffP[plane + p4];
        #pragma unroll
        for (int q = 1; q < 4; ++q) {
            float4 v = *(const float4*)&OffP[((size_t)q * 4 * 18) * HW + plane + p4];
            s.x += v.x; s.y += v.y; s.z += v.z; s.w += v.w;
        }
        s.x += bias; s.y += bias; s.z += bias; s.w += bias;
        *(float4*)&Off[plane + p4] = s;
    }
}

// ------------- deformable depthwise 3x3 + BN + SiLU + residual -------------
// grid (y=64, b=4, q=8). Row-group tiling: outer r=0..2 computes bilinear meta
// for 3 taps (24 regs), inner 8 channels consume them back-to-back (locality).
__global__ __launch_bounds__(256, 4) void k_deform(
    const float* __restrict__ Hh, const float* __restrict__ Off,
    const float* __restrict__ Wd, const float* __restrict__ Gb,
    const float* __restrict__ Bb, float* __restrict__ H2)
{
    const int y = blockIdx.x;
    const int b = blockIdx.y;
    const int q = blockIdx.z;
    const int tid = threadIdx.x;
    const int x = tid & 63;
    const int g = tid >> 6;
    const int pos = y * 64 + x;

    __shared__ __align__(16) float wds[9 * 32];   // [k][lc]
    __shared__ float gbs[32], bbs[32];

    for (int i = tid; i < 288; i += 256) {
        int lc = i & 31, k = i >> 5;
        wds[i] = Wd[(q * 32 + lc) * 9 + k];
    }
    if (tid < 32) {
        gbs[tid] = Gb[q * 32 + tid] * BN_RS;
        bbs[tid] = Bb[q * 32 + tid];
    }
    __syncthreads();

    float acc[8];
    #pragma unroll
    for (int j = 0; j < 8; ++j) acc[j] = 0.f;

    const float* Ob  = Off + (size_t)b * 18 * HW + pos;
    const float* hb0 = Hh + ((size_t)(b * 256 + q * 32 + g * 8) << 12);

    for (int r = 0; r < 3; ++r) {
        int   i00[3], i01[3], i10[3], i11[3];
        float w00[3], w01[3], w10[3], w11[3];
        #pragma unroll
        for (int t = 0; t < 3; ++t) {
            int k = r * 3 + t;
            float dy = Ob[(size_t)(2 * k) * HW];
            float dx = Ob[(size_t)(2 * k + 1) * HW];
            float py = (float)(y + r - 1) + dy;
            float px = (float)(x + t - 1) + dx;
            float fy0 = floorf(py), fx0 = floorf(px);
            int y0 = (int)fy0, x0 = (int)fx0;
            float fy = py - fy0, fx = px - fx0;
            int y1 = y0 + 1, x1 = x0 + 1;
            float gy0 = 1.0f - fy, gx0 = 1.0f - fx;
            bool vy0 = ((unsigned)y0 < 64u), vy1 = ((unsigned)y1 < 64u);
            bool vx0 = ((unsigned)x0 < 64u), vx1 = ((unsigned)x1 < 64u);
            int cy0 = clamp64(y0), cy1 = clamp64(y1);
            int cx0 = clamp64(x0), cx1 = clamp64(x1);
            i00[t] = cy0 * 64 + cx0; i01[t] = cy0 * 64 + cx1;
            i10[t] = cy1 * 64 + cx0; i11[t] = cy1 * 64 + cx1;
            w00[t] = (vy0 && vx0) ? gy0 * gx0 : 0.0f;
            w01[t] = (vy0 && vx1) ? gy0 * fx  : 0.0f;
            w10[t] = (vy1 && vx0) ? fy  * gx0 : 0.0f;
            w11[t] = (vy1 && vx1) ? fy  * fx  : 0.0f;
        }
        #pragma unroll
        for (int j = 0; j < 8; ++j) {
            const float* hb = hb0 + ((size_t)j << 12);
            float a = acc[j];
            #pragma unroll
            for (int t = 0; t < 3; ++t) {
                float val = hb[i00[t]] * w00[t] + hb[i01[t]] * w01[t]
                          + hb[i10[t]] * w10[t] + hb[i11[t]] * w11[t];
                a = fmaf(val, wds[(r * 3 + t) * 32 + g * 8 + j], a);
            }
            acc[j] = a;
        }
    }

    #pragma unroll
    for (int j = 0; j < 8; ++j) {
        int lc = g * 8 + j;
        const float* hb = hb0 + ((size_t)j << 12);
        float t = fmaf(acc[j], gbs[lc], bbs[lc]);
        H2[((size_t)(b * 256 + q * 32 + lc) << 12) + pos] = silu_f(t) + hb[pos];
    }
}

// ---------------- SE: global mean over HxW ----------------
__global__ __launch_bounds__(256) void k_se_reduce(
    const float* __restrict__ Y, float* __restrict__ sb)
{
    const int bc = blockIdx.x;
    const float4* p = (const float4*)(Y + (size_t)bc * HW);
    int tid = threadIdx.x;
    float s = 0.f;
    #pragma unroll
    for (int it = 0; it < 4; ++it) {
        float4 v = p[tid + it * 256];
        s += v.x + v.y + v.z + v.w;
    }
    #pragma unroll
    for (int o = 32; o > 0; o >>= 1) s += __shfl_down(s, o);
    __shared__ float red[4];
    if ((tid & 63) == 0) red[tid >> 6] = s;
    __syncthreads();
    if (tid == 0) sb[bc] = (red[0] + red[1] + red[2] + red[3]) * (1.0f / 4096.0f);
}

// ---------------- SE: fc1(silu) + fc2(sigmoid) ----------------
__global__ __launch_bounds__(256) void k_se_fc(
    const float* __restrict__ sb, const float* __restrict__ wf1,
    const float* __restrict__ bf1, const float* __restrict__ wf2,
    const float* __restrict__ bf2, float* __restrict__ s2)
{
    const int b = blockIdx.x;
    const int t = threadIdx.x;
    __shared__ float sv[512];
    __shared__ float s1[32];
    sv[t]       = sb[b * 512 + t];
    sv[t + 256] = sb[b * 512 + t + 256];
    __syncthreads();
    if (t < 32) {
        float a = bf1[t];
        const float* w = wf1 + t * 512;
        for (int i = 0; i < 512; ++i) a = fmaf(w[i], sv[i], a);
        s1[t] = silu_f(a);
    }
    __syncthreads();
    #pragma unroll
    for (int it = 0; it < 2; ++it) {
        int co = t + it * 256;
        float a = bf2[co];
        const float* w = wf2 + co * 32;
        #pragma unroll
        for (int i = 0; i < 32; ++i) a = fmaf(w[i], s1[i], a);
        s2[b * 512 + co] = 1.0f / (1.0f + __expf(-a));
    }
}

// ---------------- final: out *= s ----------------
__global__ __launch_bounds__(256) void k_se_scale(
    float* __restrict__ Y, const float* __restrict__ s2)
{
    size_t i = (size_t)blockIdx.x * 256 + threadIdx.x;
    int bc = (int)(i >> 10);
    float sc = s2[bc];
    float4 v = ((float4*)Y)[i];
    v.x *= sc; v.y *= sc; v.z *= sc; v.w *= sc;
    ((float4*)Y)[i] = v;
}

extern "C" void kernel_launch(void* const* d_in, const int* in_sizes, int n_in,
                              void* d_out, int out_size, void* d_ws, size_t ws_size,
                              hipStream_t stream)
{
    const float* x   = (const float*)d_in[0];
    const float* w1  = (const float*)d_in[1];
    const float* g1  = (const float*)d_in[2];
    const float* b1  = (const float*)d_in[3];
    const float* wof = (const float*)d_in[4];
    const float* bof = (const float*)d_in[5];
    const float* wdw = (const float*)d_in[6];
    const float* gb  = (const float*)d_in[7];
    const float* bbv = (const float*)d_in[8];
    const float* w2  = (const float*)d_in[9];
    const float* g2  = (const float*)d_in[10];
    const float* b2  = (const float*)d_in[11];
    const float* wf1 = (const float*)d_in[12];
    const float* bf1 = (const float*)d_in[13];
    const float* wf2 = (const float*)d_in[14];
    const float* bf2 = (const float*)d_in[15];
    float* out = (float*)d_out;

    const size_t n_h    = 4ull * 256 * HW;        // 4,194,304
    const size_t n_offp = 4ull * 4 * 18 * HW;     // 1,179,648
    const size_t n_off  = 4ull * 18 * HW;         //   294,912
    float* ws = (float*)d_ws;
    float *h, *offp, *offc, *h2, *sb, *s2;
    size_t need = (2 * n_h + n_offp + n_off + 4096) * sizeof(float);
    if (ws_size >= need) {
        h = ws; offp = h + n_h; offc = offp + n_offp; h2 = offc + n_off;
        sb = h2 + n_h; s2 = sb + 2048;
    } else {
        h = out;  // dead before conv2 writes out
        offp = ws; offc = offp + n_offp; h2 = offc + n_off;
        sb = h2 + n_h; s2 = sb + 2048;
    }

    k_conv1x1_mfma<256, 512><<<dim3(64, 4, 4), 256, 0, stream>>>(x, w1, g1, b1, h);
    k_conv_off<<<dim3(64, 4, 4), 256, 0, stream>>>(h, wof, offp);
    k_off_combine<<<72, 256, 0, stream>>>(offp, bof, offc);
    k_deform<<<dim3(64, 4, 8), 256, 0, stream>>>(h, offc, wdw, gb, bbv, h2);
    k_conv1x1_mfma<512, 256><<<dim3(64, 8, 4), 256, 0, stream>>>(h2, w2, g2, b2, out);
    k_se_reduce<<<2048, 256, 0, stream>>>(out, sb);
    k_se_fc<<<4, 256, 0, stream>>>(sb, wf1, bf1, wf2, bf2, s2);
    k_se_scale<<<8192, 256, 0, stream>>>(out, s2);
}

// Round 7
// 234.447 us; speedup vs baseline: 1.1331x; 1.0081x over previous
//
#include <hip/hip_runtime.h>

#define HW 4096
#define BN_RS 0.9999950000374998f   // 1/sqrt(1+1e-5)

typedef __attribute__((ext_vector_type(8))) short  short8;
typedef __attribute__((ext_vector_type(8))) unsigned short ushort8;
typedef __attribute__((ext_vector_type(4))) float  f32x4;

__device__ __forceinline__ float silu_f(float v) { return v / (1.0f + __expf(-v)); }
__device__ __forceinline__ int clamp64(int v) { return v < 0 ? 0 : (v > 63 ? 63 : v); }
__device__ __forceinline__ unsigned short f2bf(float f) {
    union { float f; unsigned u; } v; v.f = f;
    unsigned r = v.u + 0x7fff + ((v.u >> 16) & 1);   // RNE
    return (unsigned short)(r >> 16);
}

// ---------------- 1x1 conv + BN + SiLU, bf16 MFMA GEMM ----------------
// Block: 64co x 64pos tile, 4 waves as 2x2 of 32x32, BK=32.
template<int CO, int CIN>
__global__ __launch_bounds__(256) void k_conv1x1_mfma(
    const float* __restrict__ X, const float* __restrict__ Wt,
    const float* __restrict__ gg, const float* __restrict__ bb,
    float* __restrict__ Y)
{
    const int b  = blockIdx.z;
    const int p0 = blockIdx.x * 64;
    const int c0 = blockIdx.y * 64;
    const int tid  = threadIdx.x;
    const int wave = tid >> 6, lane = tid & 63;
    const int wm = wave >> 1, wn = wave & 1;
    const int lrow = lane & 15, lkg = lane >> 4;

    __shared__ __align__(16) unsigned short As[64 * 40];  // [co][k]
    __shared__ __align__(16) unsigned short Bs[64 * 40];  // [pos][k], k-group XOR swizzle

    const float* Xb = X + (size_t)b * CIN * HW;

    f32x4 acc[2][2];
    #pragma unroll
    for (int i = 0; i < 2; ++i)
        #pragma unroll
        for (int j = 0; j < 2; ++j) acc[i][j] = (f32x4){0.f, 0.f, 0.f, 0.f};

    const int arow = tid >> 2, akc = (tid & 3) * 8;

    for (int k0 = 0; k0 < CIN; k0 += 32) {
        __syncthreads();
        {
            const float* wp = &Wt[(size_t)(c0 + arow) * CIN + k0 + akc];
            float4 v0 = *(const float4*)wp;
            float4 v1 = *(const float4*)(wp + 4);
            ushort8 u;
            u[0] = f2bf(v0.x); u[1] = f2bf(v0.y); u[2] = f2bf(v0.z); u[3] = f2bf(v0.w);
            u[4] = f2bf(v1.x); u[5] = f2bf(v1.y); u[6] = f2bf(v1.z); u[7] = f2bf(v1.w);
            *(ushort8*)&As[arow * 40 + akc] = u;
        }
        #pragma unroll
        for (int it = 0; it < 2; ++it) {
            int i  = tid + it * 256;          // 0..511
            int kk = i >> 4;                  // 0..31
            int p4 = (i & 15) * 4;
            float4 v = *(const float4*)&Xb[(size_t)(k0 + kk) * HW + p0 + p4];
            int kg = kk >> 3, kl = kk & 7;
            float vv[4] = {v.x, v.y, v.z, v.w};
            #pragma unroll
            for (int jj = 0; jj < 4; ++jj) {
                int pos = p4 + jj;
                int kgs = kg ^ ((pos >> 2) & 3);
                Bs[pos * 40 + kgs * 8 + kl] = f2bf(vv[jj]);
            }
        }
        __syncthreads();

        short8 aF[2], bF[2];
        #pragma unroll
        for (int mi = 0; mi < 2; ++mi)
            aF[mi] = *(const short8*)&As[(wm * 32 + mi * 16 + lrow) * 40 + lkg * 8];
        #pragma unroll
        for (int ni = 0; ni < 2; ++ni) {
            int pos = wn * 32 + ni * 16 + lrow;
            int kgs = lkg ^ ((pos >> 2) & 3);
            bF[ni] = *(const short8*)&Bs[pos * 40 + kgs * 8];
        }
        #pragma unroll
        for (int mi = 0; mi < 2; ++mi)
            #pragma unroll
            for (int ni = 0; ni < 2; ++ni)
                acc[mi][ni] = __builtin_amdgcn_mfma_f32_16x16x32_bf16(
                    aF[mi], bF[ni], acc[mi][ni], 0, 0, 0);
    }

    // epilogue: D row = (lane>>4)*4 + reg, col = lane&15
    #pragma unroll
    for (int mi = 0; mi < 2; ++mi) {
        #pragma unroll
        for (int r = 0; r < 4; ++r) {
            int co = c0 + wm * 32 + mi * 16 + lkg * 4 + r;
            float s  = gg[co] * BN_RS;
            float bi = bb[co];
            size_t rowb = ((size_t)b * CO + co) * HW + p0 + wn * 32 + lrow;
            Y[rowb]      = silu_f(fmaf(acc[mi][0][r], s, bi));
            Y[rowb + 16] = silu_f(fmaf(acc[mi][1][r], s, bi));
        }
    }
}

// -------- 3x3 conv (256 -> 18), pad 1, channel-split partial sums --------
__global__ __launch_bounds__(256) void k_conv_off(
    const float* __restrict__ Hh, const float* __restrict__ Wo,
    float* __restrict__ OffP)
{
    const int y = blockIdx.x;
    const int b = blockIdx.y;
    const int q = blockIdx.z;
    const int tid = threadIdx.x;
    const int x = tid & 63;
    const int g = tid >> 6;

    __shared__ __align__(16) float hs[3][32][66];
    __shared__ __align__(16) float ws[18][32][12];

    if (tid < 96) {
        int r = tid >> 5, ci = tid & 31;
        hs[r][ci][0] = 0.f; hs[r][ci][65] = 0.f;
    }

    float acc[5] = {0.f, 0.f, 0.f, 0.f, 0.f};
    const float* Hb = Hh + (size_t)b * 256 * HW;

    for (int cc = 0; cc < 2; ++cc) {
        const int c0 = q * 64 + cc * 32;
        __syncthreads();
        for (int i = tid; i < 5184; i += 256) {
            int co = i / 288, r = i % 288;
            int ci = r / 9, t = r - ci * 9;
            ws[co][ci][t] = Wo[(size_t)co * 2304 + (size_t)(c0 + ci) * 9 + t];
        }
        #pragma unroll
        for (int it = 0; it < 6; ++it) {
            int i   = tid + it * 256;
            int r   = i >> 9;
            int rem = i & 511;
            int ci  = rem >> 4;
            int x4  = (rem & 15) << 2;
            int yy  = y + r - 1;
            float4 v = make_float4(0.f, 0.f, 0.f, 0.f);
            if ((unsigned)yy < 64u)
                v = *(const float4*)&Hb[(size_t)(c0 + ci) * HW + yy * 64 + x4];
            hs[r][ci][1 + x4] = v.x;
            hs[r][ci][2 + x4] = v.y;
            hs[r][ci][3 + x4] = v.z;
            hs[r][ci][4 + x4] = v.w;
        }
        __syncthreads();
        #pragma unroll 2
        for (int ci = 0; ci < 32; ++ci) {
            float v[9];
            #pragma unroll
            for (int r = 0; r < 3; ++r) {
                v[r * 3 + 0] = hs[r][ci][x];
                v[r * 3 + 1] = hs[r][ci][x + 1];
                v[r * 3 + 2] = hs[r][ci][x + 2];
            }
            #pragma unroll
            for (int j = 0; j < 5; ++j) {
                int co = g + (j << 2);
                if (co < 18) {
                    const float4 w0 = *(const float4*)&ws[co][ci][0];
                    const float4 w1 = *(const float4*)&ws[co][ci][4];
                    const float  w8 = ws[co][ci][8];
                    float a = acc[j];
                    a = fmaf(w0.x, v[0], a); a = fmaf(w0.y, v[1], a);
                    a = fmaf(w0.z, v[2], a); a = fmaf(w0.w, v[3], a);
                    a = fmaf(w1.x, v[4], a); a = fmaf(w1.y, v[5], a);
                    a = fmaf(w1.z, v[6], a); a = fmaf(w1.w, v[7], a);
                    a = fmaf(w8,   v[8], a);
                    acc[j] = a;
                }
            }
        }
    }
    #pragma unroll
    for (int j = 0; j < 5; ++j) {
        int co = g + (j << 2);
        if (co < 18)
            OffP[(((size_t)q * 4 + b) * 18 + co) * HW + y * 64 + x] = acc[j];
    }
}

// -------- combine 4 channel-split partials + bias -> final offsets --------
__global__ __launch_bounds__(256) void k_off_combine(
    const float* __restrict__ OffP, const float* __restrict__ Bo,
    float* __restrict__ Off)
{
    const int bt = blockIdx.x;         // b*18 + t, 72 blocks
    const int b = bt / 18, t = bt - b * 18;
    const float bias = Bo[t];
    const size_t plane = ((size_t)b * 18 + t) * HW;
    #pragma unroll
    for (int it = 0; it < 4; ++it) {
        int p4 = (threadIdx.x + it * 256) * 4;
        float4 s = *(const float4*)&OffP[plane + p4];
        #pragma unroll
        for (int q = 1; q < 4; ++q) {
            float4 v = *(const float4*)&OffP[((size_t)q * 4 * 18) * HW + plane + p4];
            s.x += v.x; s.y += v.y; s.z += v.z; s.w += v.w;
        }
        s.x += bias; s.y += bias; s.z += bias; s.w += bias;
        *(float4*)&Off[plane + p4] = s;
    }
}

// ------------- deformable depthwise 3x3 + BN + SiLU + residual -------------
// 1D grid 2048, idx = y*32 + (b*8+q)  =>  XCD = idx%8 = q: all 256 blocks of a
// q-group pin to one XCD; its L2 retains the group's 32 planes (2MB) + offsets
// (1.15MB) across y, turning halo re-reads into L2 hits. H2 stores are
// non-temporal so the streaming output doesn't evict the gather planes.
__global__ __launch_bounds__(256, 4) void k_deform(
    const float* __restrict__ Hh, const float* __restrict__ Off,
    const float* __restrict__ Wd, const float* __restrict__ Gb,
    const float* __restrict__ Bb, float* __restrict__ H2)
{
    const int idx = blockIdx.x;
    const int bq  = idx & 31;
    const int y   = idx >> 5;
    const int b   = bq >> 3;
    const int q   = bq & 7;
    const int tid = threadIdx.x;
    const int x = tid & 63;
    const int g = tid >> 6;
    const int pos = y * 64 + x;

    __shared__ __align__(16) float wds[9 * 32];   // [k][lc]
    __shared__ float gbs[32], bbs[32];

    for (int i = tid; i < 288; i += 256) {
        int lc = i & 31, k = i >> 5;
        wds[i] = Wd[(q * 32 + lc) * 9 + k];
    }
    if (tid < 32) {
        gbs[tid] = Gb[q * 32 + tid] * BN_RS;
        bbs[tid] = Bb[q * 32 + tid];
    }
    __syncthreads();

    float acc[8];
    #pragma unroll
    for (int j = 0; j < 8; ++j) acc[j] = 0.f;

    const float* Ob  = Off + (size_t)b * 18 * HW + pos;
    const float* hb0 = Hh + ((size_t)(b * 256 + q * 32 + g * 8) << 12);

    for (int r = 0; r < 3; ++r) {
        int   i00[3], i01[3], i10[3], i11[3];
        float w00[3], w01[3], w10[3], w11[3];
        #pragma unroll
        for (int t = 0; t < 3; ++t) {
            int k = r * 3 + t;
            float dy = Ob[(size_t)(2 * k) * HW];
            float dx = Ob[(size_t)(2 * k + 1) * HW];
            float py = (float)(y + r - 1) + dy;
            float px = (float)(x + t - 1) + dx;
            float fy0 = floorf(py), fx0 = floorf(px);
            int y0 = (int)fy0, x0 = (int)fx0;
            float fy = py - fy0, fx = px - fx0;
            int y1 = y0 + 1, x1 = x0 + 1;
            float gy0 = 1.0f - fy, gx0 = 1.0f - fx;
            bool vy0 = ((unsigned)y0 < 64u), vy1 = ((unsigned)y1 < 64u);
            bool vx0 = ((unsigned)x0 < 64u), vx1 = ((unsigned)x1 < 64u);
            int cy0 = clamp64(y0), cy1 = clamp64(y1);
            int cx0 = clamp64(x0), cx1 = clamp64(x1);
            i00[t] = cy0 * 64 + cx0; i01[t] = cy0 * 64 + cx1;
            i10[t] = cy1 * 64 + cx0; i11[t] = cy1 * 64 + cx1;
            w00[t] = (vy0 && vx0) ? gy0 * gx0 : 0.0f;
            w01[t] = (vy0 && vx1) ? gy0 * fx  : 0.0f;
            w10[t] = (vy1 && vx0) ? fy  * gx0 : 0.0f;
            w11[t] = (vy1 && vx1) ? fy  * fx  : 0.0f;
        }
        #pragma unroll
        for (int j = 0; j < 8; ++j) {
            const float* hb = hb0 + ((size_t)j << 12);
            float a = acc[j];
            #pragma unroll
            for (int t = 0; t < 3; ++t) {
                float val = hb[i00[t]] * w00[t] + hb[i01[t]] * w01[t]
                          + hb[i10[t]] * w10[t] + hb[i11[t]] * w11[t];
                a = fmaf(val, wds[(r * 3 + t) * 32 + g * 8 + j], a);
            }
            acc[j] = a;
        }
    }

    #pragma unroll
    for (int j = 0; j < 8; ++j) {
        int lc = g * 8 + j;
        const float* hb = hb0 + ((size_t)j << 12);
        float t = fmaf(acc[j], gbs[lc], bbs[lc]);
        __builtin_nontemporal_store(silu_f(t) + hb[pos],
            &H2[((size_t)(b * 256 + q * 32 + lc) << 12) + pos]);
    }
}

// ---------------- SE: global mean over HxW ----------------
__global__ __launch_bounds__(256) void k_se_reduce(
    const float* __restrict__ Y, float* __restrict__ sb)
{
    const int bc = blockIdx.x;
    const float4* p = (const float4*)(Y + (size_t)bc * HW);
    int tid = threadIdx.x;
    float s = 0.f;
    #pragma unroll
    for (int it = 0; it < 4; ++it) {
        float4 v = p[tid + it * 256];
        s += v.x + v.y + v.z + v.w;
    }
    #pragma unroll
    for (int o = 32; o > 0; o >>= 1) s += __shfl_down(s, o);
    __shared__ float red[4];
    if ((tid & 63) == 0) red[tid >> 6] = s;
    __syncthreads();
    if (tid == 0) sb[bc] = (red[0] + red[1] + red[2] + red[3]) * (1.0f / 4096.0f);
}

// ---------------- SE: fc1(silu) + fc2(sigmoid) ----------------
__global__ __launch_bounds__(256) void k_se_fc(
    const float* __restrict__ sb, const float* __restrict__ wf1,
    const float* __restrict__ bf1, const float* __restrict__ wf2,
    const float* __restrict__ bf2, float* __restrict__ s2)
{
    const int b = blockIdx.x;
    const int t = threadIdx.x;
    __shared__ float sv[512];
    __shared__ float s1[32];
    sv[t]       = sb[b * 512 + t];
    sv[t + 256] = sb[b * 512 + t + 256];
    __syncthreads();
    if (t < 32) {
        float a = bf1[t];
        const float* w = wf1 + t * 512;
        for (int i = 0; i < 512; ++i) a = fmaf(w[i], sv[i], a);
        s1[t] = silu_f(a);
    }
    __syncthreads();
    #pragma unroll
    for (int it = 0; it < 2; ++it) {
        int co = t + it * 256;
        float a = bf2[co];
        const float* w = wf2 + co * 32;
        #pragma unroll
        for (int i = 0; i < 32; ++i) a = fmaf(w[i], s1[i], a);
        s2[b * 512 + co] = 1.0f / (1.0f + __expf(-a));
    }
}

// ---------------- final: out *= s ----------------
__global__ __launch_bounds__(256) void k_se_scale(
    float* __restrict__ Y, const float* __restrict__ s2)
{
    size_t i = (size_t)blockIdx.x * 256 + threadIdx.x;
    int bc = (int)(i >> 10);
    float sc = s2[bc];
    float4 v = ((float4*)Y)[i];
    v.x *= sc; v.y *= sc; v.z *= sc; v.w *= sc;
    ((float4*)Y)[i] = v;
}

extern "C" void kernel_launch(void* const* d_in, const int* in_sizes, int n_in,
                              void* d_out, int out_size, void* d_ws, size_t ws_size,
                              hipStream_t stream)
{
    const float* x   = (const float*)d_in[0];
    const float* w1  = (const float*)d_in[1];
    const float* g1  = (const float*)d_in[2];
    const float* b1  = (const float*)d_in[3];
    const float* wof = (const float*)d_in[4];
    const float* bof = (const float*)d_in[5];
    const float* wdw = (const float*)d_in[6];
    const float* gb  = (const float*)d_in[7];
    const float* bbv = (const float*)d_in[8];
    const float* w2  = (const float*)d_in[9];
    const float* g2  = (const float*)d_in[10];
    const float* b2  = (const float*)d_in[11];
    const float* wf1 = (const float*)d_in[12];
    const float* bf1 = (const float*)d_in[13];
    const float* wf2 = (const float*)d_in[14];
    const float* bf2 = (const float*)d_in[15];
    float* out = (float*)d_out;

    const size_t n_h    = 4ull * 256 * HW;        // 4,194,304
    const size_t n_offp = 4ull * 4 * 18 * HW;     // 1,179,648
    const size_t n_off  = 4ull * 18 * HW;         //   294,912
    float* ws = (float*)d_ws;
    float *h, *offp, *offc, *h2, *sb, *s2;
    size_t need = (2 * n_h + n_offp + n_off + 4096) * sizeof(float);
    if (ws_size >= need) {
        h = ws; offp = h + n_h; offc = offp + n_offp; h2 = offc + n_off;
        sb = h2 + n_h; s2 = sb + 2048;
    } else {
        h = out;  // dead before conv2 writes out
        offp = ws; offc = offp + n_offp; h2 = offc + n_off;
        sb = h2 + n_h; s2 = sb + 2048;
    }

    k_conv1x1_mfma<256, 512><<<dim3(64, 4, 4), 256, 0, stream>>>(x, w1, g1, b1, h);
    k_conv_off<<<dim3(64, 4, 4), 256, 0, stream>>>(h, wof, offp);
    k_off_combine<<<72, 256, 0, stream>>>(offp, bof, offc);
    k_deform<<<2048, 256, 0, stream>>>(h, offc, wdw, gb, bbv, h2);
    k_conv1x1_mfma<512, 256><<<dim3(64, 8, 4), 256, 0, stream>>>(h2, w2, g2, b2, out);
    k_se_reduce<<<2048, 256, 0, stream>>>(out, sb);
    k_se_fc<<<4, 256, 0, stream>>>(sb, wf1, bf1, wf2, bf2, s2);
    k_se_scale<<<8192, 256, 0, stream>>>(out, s2);
}

// Round 8
// 214.390 us; speedup vs baseline: 1.2392x; 1.0936x over previous
//
#include <hip/hip_runtime.h>

#define HW 4096
#define BN_RS 0.9999950000374998f   // 1/sqrt(1+1e-5)

typedef __attribute__((ext_vector_type(8))) short  short8;
typedef __attribute__((ext_vector_type(8))) unsigned short ushort8;
typedef __attribute__((ext_vector_type(4))) float  f32x4;
typedef __attribute__((ext_vector_type(2), aligned(4))) float f32x2u;  // 4B-aligned float2

__device__ __forceinline__ float silu_f(float v) { return v / (1.0f + __expf(-v)); }
__device__ __forceinline__ int clamp64(int v) { return v < 0 ? 0 : (v > 63 ? 63 : v); }
__device__ __forceinline__ unsigned short f2bf(float f) {
    union { float f; unsigned u; } v; v.f = f;
    unsigned r = v.u + 0x7fff + ((v.u >> 16) & 1);   // RNE
    return (unsigned short)(r >> 16);
}

// ---------------- 1x1 conv + BN + SiLU, bf16 MFMA GEMM ----------------
template<int CO, int CIN>
__global__ __launch_bounds__(256) void k_conv1x1_mfma(
    const float* __restrict__ X, const float* __restrict__ Wt,
    const float* __restrict__ gg, const float* __restrict__ bb,
    float* __restrict__ Y)
{
    const int b  = blockIdx.z;
    const int p0 = blockIdx.x * 64;
    const int c0 = blockIdx.y * 64;
    const int tid  = threadIdx.x;
    const int wave = tid >> 6, lane = tid & 63;
    const int wm = wave >> 1, wn = wave & 1;
    const int lrow = lane & 15, lkg = lane >> 4;

    __shared__ __align__(16) unsigned short As[64 * 40];  // [co][k]
    __shared__ __align__(16) unsigned short Bs[64 * 40];  // [pos][k], k-group XOR swizzle

    const float* Xb = X + (size_t)b * CIN * HW;

    f32x4 acc[2][2];
    #pragma unroll
    for (int i = 0; i < 2; ++i)
        #pragma unroll
        for (int j = 0; j < 2; ++j) acc[i][j] = (f32x4){0.f, 0.f, 0.f, 0.f};

    const int arow = tid >> 2, akc = (tid & 3) * 8;

    for (int k0 = 0; k0 < CIN; k0 += 32) {
        __syncthreads();
        {
            const float* wp = &Wt[(size_t)(c0 + arow) * CIN + k0 + akc];
            float4 v0 = *(const float4*)wp;
            float4 v1 = *(const float4*)(wp + 4);
            ushort8 u;
            u[0] = f2bf(v0.x); u[1] = f2bf(v0.y); u[2] = f2bf(v0.z); u[3] = f2bf(v0.w);
            u[4] = f2bf(v1.x); u[5] = f2bf(v1.y); u[6] = f2bf(v1.z); u[7] = f2bf(v1.w);
            *(ushort8*)&As[arow * 40 + akc] = u;
        }
        #pragma unroll
        for (int it = 0; it < 2; ++it) {
            int i  = tid + it * 256;          // 0..511
            int kk = i >> 4;                  // 0..31
            int p4 = (i & 15) * 4;
            float4 v = *(const float4*)&Xb[(size_t)(k0 + kk) * HW + p0 + p4];
            int kg = kk >> 3, kl = kk & 7;
            float vv[4] = {v.x, v.y, v.z, v.w};
            #pragma unroll
            for (int jj = 0; jj < 4; ++jj) {
                int pos = p4 + jj;
                int kgs = kg ^ ((pos >> 2) & 3);
                Bs[pos * 40 + kgs * 8 + kl] = f2bf(vv[jj]);
            }
        }
        __syncthreads();

        short8 aF[2], bF[2];
        #pragma unroll
        for (int mi = 0; mi < 2; ++mi)
            aF[mi] = *(const short8*)&As[(wm * 32 + mi * 16 + lrow) * 40 + lkg * 8];
        #pragma unroll
        for (int ni = 0; ni < 2; ++ni) {
            int pos = wn * 32 + ni * 16 + lrow;
            int kgs = lkg ^ ((pos >> 2) & 3);
            bF[ni] = *(const short8*)&Bs[pos * 40 + kgs * 8];
        }
        #pragma unroll
        for (int mi = 0; mi < 2; ++mi)
            #pragma unroll
            for (int ni = 0; ni < 2; ++ni)
                acc[mi][ni] = __builtin_amdgcn_mfma_f32_16x16x32_bf16(
                    aF[mi], bF[ni], acc[mi][ni], 0, 0, 0);
    }

    // epilogue: D row = (lane>>4)*4 + reg, col = lane&15
    #pragma unroll
    for (int mi = 0; mi < 2; ++mi) {
        #pragma unroll
        for (int r = 0; r < 4; ++r) {
            int co = c0 + wm * 32 + mi * 16 + lkg * 4 + r;
            float s  = gg[co] * BN_RS;
            float bi = bb[co];
            size_t rowb = ((size_t)b * CO + co) * HW + p0 + wn * 32 + lrow;
            Y[rowb]      = silu_f(fmaf(acc[mi][0][r], s, bi));
            Y[rowb + 16] = silu_f(fmaf(acc[mi][1][r], s, bi));
        }
    }
}

// -------- 3x3 conv (256 -> 18), pad 1, channel-split partial sums --------
__global__ __launch_bounds__(256) void k_conv_off(
    const float* __restrict__ Hh, const float* __restrict__ Wo,
    float* __restrict__ OffP)
{
    const int y = blockIdx.x;
    const int b = blockIdx.y;
    const int q = blockIdx.z;
    const int tid = threadIdx.x;
    const int x = tid & 63;
    const int g = tid >> 6;

    __shared__ __align__(16) float hs[3][32][66];
    __shared__ __align__(16) float ws[18][32][12];

    if (tid < 96) {
        int r = tid >> 5, ci = tid & 31;
        hs[r][ci][0] = 0.f; hs[r][ci][65] = 0.f;
    }

    float acc[5] = {0.f, 0.f, 0.f, 0.f, 0.f};
    const float* Hb = Hh + (size_t)b * 256 * HW;

    for (int cc = 0; cc < 2; ++cc) {
        const int c0 = q * 64 + cc * 32;
        __syncthreads();
        for (int i = tid; i < 5184; i += 256) {
            int co = i / 288, r = i % 288;
            int ci = r / 9, t = r - ci * 9;
            ws[co][ci][t] = Wo[(size_t)co * 2304 + (size_t)(c0 + ci) * 9 + t];
        }
        #pragma unroll
        for (int it = 0; it < 6; ++it) {
            int i   = tid + it * 256;
            int r   = i >> 9;
            int rem = i & 511;
            int ci  = rem >> 4;
            int x4  = (rem & 15) << 2;
            int yy  = y + r - 1;
            float4 v = make_float4(0.f, 0.f, 0.f, 0.f);
            if ((unsigned)yy < 64u)
                v = *(const float4*)&Hb[(size_t)(c0 + ci) * HW + yy * 64 + x4];
            hs[r][ci][1 + x4] = v.x;
            hs[r][ci][2 + x4] = v.y;
            hs[r][ci][3 + x4] = v.z;
            hs[r][ci][4 + x4] = v.w;
        }
        __syncthreads();
        #pragma unroll 2
        for (int ci = 0; ci < 32; ++ci) {
            float v[9];
            #pragma unroll
            for (int r = 0; r < 3; ++r) {
                v[r * 3 + 0] = hs[r][ci][x];
                v[r * 3 + 1] = hs[r][ci][x + 1];
                v[r * 3 + 2] = hs[r][ci][x + 2];
            }
            #pragma unroll
            for (int j = 0; j < 5; ++j) {
                int co = g + (j << 2);
                if (co < 18) {
                    const float4 w0 = *(const float4*)&ws[co][ci][0];
                    const float4 w1 = *(const float4*)&ws[co][ci][4];
                    const float  w8 = ws[co][ci][8];
                    float a = acc[j];
                    a = fmaf(w0.x, v[0], a); a = fmaf(w0.y, v[1], a);
                    a = fmaf(w0.z, v[2], a); a = fmaf(w0.w, v[3], a);
                    a = fmaf(w1.x, v[4], a); a = fmaf(w1.y, v[5], a);
                    a = fmaf(w1.z, v[6], a); a = fmaf(w1.w, v[7], a);
                    a = fmaf(w8,   v[8], a);
                    acc[j] = a;
                }
            }
        }
    }
    #pragma unroll
    for (int j = 0; j < 5; ++j) {
        int co = g + (j << 2);
        if (co < 18)
            OffP[(((size_t)q * 4 + b) * 18 + co) * HW + y * 64 + x] = acc[j];
    }
}

// -------- combine 4 channel-split partials + bias -> final offsets --------
__global__ __launch_bounds__(256) void k_off_combine(
    const float* __restrict__ OffP, const float* __restrict__ Bo,
    float* __restrict__ Off)
{
    const int bt = blockIdx.x;         // b*18 + t, 72 blocks
    const int b = bt / 18, t = bt - b * 18;
    const float bias = Bo[t];
    const size_t plane = ((size_t)b * 18 + t) * HW;
    #pragma unroll
    for (int it = 0; it < 4; ++it) {
        int p4 = (threadIdx.x + it * 256) * 4;
        float4 s = *(const float4*)&OffP[plane + p4];
        #pragma unroll
        for (int q = 1; q < 4; ++q) {
            float4 v = *(const float4*)&OffP[((size_t)q * 4 * 18) * HW + plane + p4];
            s.x += v.x; s.y += v.y; s.z += v.z; s.w += v.w;
        }
        s.x += bias; s.y += bias; s.z += bias; s.w += bias;
        *(float4*)&Off[plane + p4] = s;
    }
}

// ------------- deformable depthwise 3x3 + BN + SiLU + residual -------------
// XCD-pinned grid (idx%8 = q). Paired-corner gathers: the two x-corners of a
// tap are adjacent floats -> one unaligned float2 load + 2 cndmask selects,
// halving VMEM gather instructions (the measured bottleneck).
__global__ __launch_bounds__(256, 4) void k_deform(
    const float* __restrict__ Hh, const float* __restrict__ Off,
    const float* __restrict__ Wd, const float* __restrict__ Gb,
    const float* __restrict__ Bb, float* __restrict__ H2)
{
    const int idx = blockIdx.x;
    const int bq  = idx & 31;
    const int y   = idx >> 5;
    const int b   = bq >> 3;
    const int q   = bq & 7;
    const int tid = threadIdx.x;
    const int x = tid & 63;
    const int g = tid >> 6;
    const int pos = y * 64 + x;

    __shared__ __align__(16) float wds[9 * 32];   // [k][lc]
    __shared__ float gbs[32], bbs[32];

    for (int i = tid; i < 288; i += 256) {
        int lc = i & 31, k = i >> 5;
        wds[i] = Wd[(q * 32 + lc) * 9 + k];
    }
    if (tid < 32) {
        gbs[tid] = Gb[q * 32 + tid] * BN_RS;
        bbs[tid] = Bb[q * 32 + tid];
    }
    __syncthreads();

    float acc[8];
    #pragma unroll
    for (int j = 0; j < 8; ++j) acc[j] = 0.f;

    const float* Ob  = Off + (size_t)b * 18 * HW + pos;
    const float* hb0 = Hh + ((size_t)(b * 256 + q * 32 + g * 8) << 12);

    for (int r = 0; r < 3; ++r) {
        int   rb0[3], rb1[3];        // cy0*64+bx, cy1*64+bx
        int   o0[3], o1[3];          // x-pair selectors (0 -> .x, 1 -> .y)
        float wy0[3], wy1[3], wx0[3], wx1[3];
        #pragma unroll
        for (int t = 0; t < 3; ++t) {
            int k = r * 3 + t;
            float dy = Ob[(size_t)(2 * k) * HW];
            float dx = Ob[(size_t)(2 * k + 1) * HW];
            float py = (float)(y + r - 1) + dy;
            float px = (float)(x + t - 1) + dx;
            float fy0 = floorf(py), fx0 = floorf(px);
            int y0 = (int)fy0, x0 = (int)fx0;
            float fy = py - fy0, fx = px - fx0;
            bool vy0 = ((unsigned)y0 < 64u), vy1 = ((unsigned)(y0 + 1) < 64u);
            bool vx0 = ((unsigned)x0 < 64u), vx1 = ((unsigned)(x0 + 1) < 64u);
            int cy0 = clamp64(y0), cy1 = clamp64(y0 + 1);
            int bx  = x0 < 0 ? 0 : (x0 > 62 ? 62 : x0);
            int d0 = x0 - bx;                 // -1, 0, or 1
            o0[t] = d0 < 0 ? 0 : d0;          // clamp to {0,1}
            int d1 = d0 + 1;                  // 0, 1, or 2
            o1[t] = d1 > 1 ? 1 : d1;
            rb0[t] = cy0 * 64 + bx;
            rb1[t] = cy1 * 64 + bx;
            wy0[t] = vy0 ? (1.0f - fy) : 0.0f;
            wy1[t] = vy1 ? fy : 0.0f;
            wx0[t] = vx0 ? (1.0f - fx) : 0.0f;
            wx1[t] = vx1 ? fx : 0.0f;
        }
        #pragma unroll
        for (int j = 0; j < 8; ++j) {
            const float* hb = hb0 + ((size_t)j << 12);
            float a = acc[j];
            #pragma unroll
            for (int t = 0; t < 3; ++t) {
                f32x2u u0 = *(const f32x2u*)(hb + rb0[t]);
                f32x2u u1 = *(const f32x2u*)(hb + rb1[t]);
                float c00 = o0[t] ? u0.y : u0.x;
                float c01 = o1[t] ? u0.y : u0.x;
                float c10 = o0[t] ? u1.y : u1.x;
                float c11 = o1[t] ? u1.y : u1.x;
                float row0 = c00 * wx0[t] + c01 * wx1[t];
                float row1 = c10 * wx0[t] + c11 * wx1[t];
                float val  = row0 * wy0[t] + row1 * wy1[t];
                a = fmaf(val, wds[(r * 3 + t) * 32 + g * 8 + j], a);
            }
            acc[j] = a;
        }
    }

    #pragma unroll
    for (int j = 0; j < 8; ++j) {
        int lc = g * 8 + j;
        const float* hb = hb0 + ((size_t)j << 12);
        float t = fmaf(acc[j], gbs[lc], bbs[lc]);
        __builtin_nontemporal_store(silu_f(t) + hb[pos],
            &H2[((size_t)(b * 256 + q * 32 + lc) << 12) + pos]);
    }
}

// ---------------- SE: global mean over HxW ----------------
__global__ __launch_bounds__(256) void k_se_reduce(
    const float* __restrict__ Y, float* __restrict__ sb)
{
    const int bc = blockIdx.x;
    const float4* p = (const float4*)(Y + (size_t)bc * HW);
    int tid = threadIdx.x;
    float s = 0.f;
    #pragma unroll
    for (int it = 0; it < 4; ++it) {
        float4 v = p[tid + it * 256];
        s += v.x + v.y + v.z + v.w;
    }
    #pragma unroll
    for (int o = 32; o > 0; o >>= 1) s += __shfl_down(s, o);
    __shared__ float red[4];
    if ((tid & 63) == 0) red[tid >> 6] = s;
    __syncthreads();
    if (tid == 0) sb[bc] = (red[0] + red[1] + red[2] + red[3]) * (1.0f / 4096.0f);
}

// ---------------- SE: fc1(silu) + fc2(sigmoid) ----------------
__global__ __launch_bounds__(256) void k_se_fc(
    const float* __restrict__ sb, const float* __restrict__ wf1,
    const float* __restrict__ bf1, const float* __restrict__ wf2,
    const float* __restrict__ bf2, float* __restrict__ s2)
{
    const int b = blockIdx.x;
    const int t = threadIdx.x;
    __shared__ float sv[512];
    __shared__ float s1[32];
    sv[t]       = sb[b * 512 + t];
    sv[t + 256] = sb[b * 512 + t + 256];
    __syncthreads();
    if (t < 32) {
        float a = bf1[t];
        const float* w = wf1 + t * 512;
        for (int i = 0; i < 512; ++i) a = fmaf(w[i], sv[i], a);
        s1[t] = silu_f(a);
    }
    __syncthreads();
    #pragma unroll
    for (int it = 0; it < 2; ++it) {
        int co = t + it * 256;
        float a = bf2[co];
        const float* w = wf2 + co * 32;
        #pragma unroll
        for (int i = 0; i < 32; ++i) a = fmaf(w[i], s1[i], a);
        s2[b * 512 + co] = 1.0f / (1.0f + __expf(-a));
    }
}

// ---------------- final: out *= s ----------------
__global__ __launch_bounds__(256) void k_se_scale(
    float* __restrict__ Y, const float* __restrict__ s2)
{
    size_t i = (size_t)blockIdx.x * 256 + threadIdx.x;
    int bc = (int)(i >> 10);
    float sc = s2[bc];
    float4 v = ((float4*)Y)[i];
    v.x *= sc; v.y *= sc; v.z *= sc; v.w *= sc;
    ((float4*)Y)[i] = v;
}

extern "C" void kernel_launch(void* const* d_in, const int* in_sizes, int n_in,
                              void* d_out, int out_size, void* d_ws, size_t ws_size,
                              hipStream_t stream)
{
    const float* x   = (const float*)d_in[0];
    const float* w1  = (const float*)d_in[1];
    const float* g1  = (const float*)d_in[2];
    const float* b1  = (const float*)d_in[3];
    const float* wof = (const float*)d_in[4];
    const float* bof = (const float*)d_in[5];
    const float* wdw = (const float*)d_in[6];
    const float* gb  = (const float*)d_in[7];
    const float* bbv = (const float*)d_in[8];
    const float* w2  = (const float*)d_in[9];
    const float* g2  = (const float*)d_in[10];
    const float* b2  = (const float*)d_in[11];
    const float* wf1 = (const float*)d_in[12];
    const float* bf1 = (const float*)d_in[13];
    const float* wf2 = (const float*)d_in[14];
    const float* bf2 = (const float*)d_in[15];
    float* out = (float*)d_out;

    const size_t n_h    = 4ull * 256 * HW;        // 4,194,304
    const size_t n_offp = 4ull * 4 * 18 * HW;     // 1,179,648
    const size_t n_off  = 4ull * 18 * HW;         //   294,912
    float* ws = (float*)d_ws;
    float *h, *offp, *offc, *h2, *sb, *s2;
    size_t need = (2 * n_h + n_offp + n_off + 4096) * sizeof(float);
    if (ws_size >= need) {
        h = ws; offp = h + n_h; offc = offp + n_offp; h2 = offc + n_off;
        sb = h2 + n_h; s2 = sb + 2048;
    } else {
        h = out;  // dead before conv2 writes out
        offp = ws; offc = offp + n_offp; h2 = offc + n_off;
        sb = h2 + n_h; s2 = sb + 2048;
    }

    k_conv1x1_mfma<256, 512><<<dim3(64, 4, 4), 256, 0, stream>>>(x, w1, g1, b1, h);
    k_conv_off<<<dim3(64, 4, 4), 256, 0, stream>>>(h, wof, offp);
    k_off_combine<<<72, 256, 0, stream>>>(offp, bof, offc);
    k_deform<<<2048, 256, 0, stream>>>(h, offc, wdw, gb, bbv, h2);
    k_conv1x1_mfma<512, 256><<<dim3(64, 8, 4), 256, 0, stream>>>(h2, w2, g2, b2, out);
    k_se_reduce<<<2048, 256, 0, stream>>>(out, sb);
    k_se_fc<<<4, 256, 0, stream>>>(sb, wf1, bf1, wf2, bf2, s2);
    k_se_scale<<<8192, 256, 0, stream>>>(out, s2);
}

// Round 9
// 175.533 us; speedup vs baseline: 1.5135x; 1.2214x over previous
//
#include <hip/hip_runtime.h>

#define HW 4096
#define BN_RS 0.9999950000374998f   // 1/sqrt(1+1e-5)

typedef __attribute__((ext_vector_type(8))) short  short8;
typedef __attribute__((ext_vector_type(8))) unsigned short ushort8;
typedef __attribute__((ext_vector_type(4))) float  f32x4;
typedef __attribute__((ext_vector_type(2), aligned(4))) float f32x2u;  // 4B-aligned float2

__device__ __forceinline__ float silu_f(float v) { return v / (1.0f + __expf(-v)); }
__device__ __forceinline__ int clamp64(int v) { return v < 0 ? 0 : (v > 63 ? 63 : v); }
__device__ __forceinline__ unsigned short f2bf(float f) {
    union { float f; unsigned u; } v; v.f = f;
    unsigned r = v.u + 0x7fff + ((v.u >> 16) & 1);   // RNE
    return (unsigned short)(r >> 16);
}

// ---------------- 1x1 conv + BN + SiLU, bf16 MFMA GEMM ----------------
template<int CO, int CIN>
__global__ __launch_bounds__(256) void k_conv1x1_mfma(
    const float* __restrict__ X, const float* __restrict__ Wt,
    const float* __restrict__ gg, const float* __restrict__ bb,
    float* __restrict__ Y)
{
    const int b  = blockIdx.z;
    const int p0 = blockIdx.x * 64;
    const int c0 = blockIdx.y * 64;
    const int tid  = threadIdx.x;
    const int wave = tid >> 6, lane = tid & 63;
    const int wm = wave >> 1, wn = wave & 1;
    const int lrow = lane & 15, lkg = lane >> 4;

    __shared__ __align__(16) unsigned short As[64 * 40];  // [co][k]
    __shared__ __align__(16) unsigned short Bs[64 * 40];  // [pos][k], k-group XOR swizzle

    const float* Xb = X + (size_t)b * CIN * HW;

    f32x4 acc[2][2];
    #pragma unroll
    for (int i = 0; i < 2; ++i)
        #pragma unroll
        for (int j = 0; j < 2; ++j) acc[i][j] = (f32x4){0.f, 0.f, 0.f, 0.f};

    const int arow = tid >> 2, akc = (tid & 3) * 8;

    for (int k0 = 0; k0 < CIN; k0 += 32) {
        __syncthreads();
        {
            const float* wp = &Wt[(size_t)(c0 + arow) * CIN + k0 + akc];
            float4 v0 = *(const float4*)wp;
            float4 v1 = *(const float4*)(wp + 4);
            ushort8 u;
            u[0] = f2bf(v0.x); u[1] = f2bf(v0.y); u[2] = f2bf(v0.z); u[3] = f2bf(v0.w);
            u[4] = f2bf(v1.x); u[5] = f2bf(v1.y); u[6] = f2bf(v1.z); u[7] = f2bf(v1.w);
            *(ushort8*)&As[arow * 40 + akc] = u;
        }
        #pragma unroll
        for (int it = 0; it < 2; ++it) {
            int i  = tid + it * 256;          // 0..511
            int kk = i >> 4;                  // 0..31
            int p4 = (i & 15) * 4;
            float4 v = *(const float4*)&Xb[(size_t)(k0 + kk) * HW + p0 + p4];
            int kg = kk >> 3, kl = kk & 7;
            float vv[4] = {v.x, v.y, v.z, v.w};
            #pragma unroll
            for (int jj = 0; jj < 4; ++jj) {
                int pos = p4 + jj;
                int kgs = kg ^ ((pos >> 2) & 3);
                Bs[pos * 40 + kgs * 8 + kl] = f2bf(vv[jj]);
            }
        }
        __syncthreads();

        short8 aF[2], bF[2];
        #pragma unroll
        for (int mi = 0; mi < 2; ++mi)
            aF[mi] = *(const short8*)&As[(wm * 32 + mi * 16 + lrow) * 40 + lkg * 8];
        #pragma unroll
        for (int ni = 0; ni < 2; ++ni) {
            int pos = wn * 32 + ni * 16 + lrow;
            int kgs = lkg ^ ((pos >> 2) & 3);
            bF[ni] = *(const short8*)&Bs[pos * 40 + kgs * 8];
        }
        #pragma unroll
        for (int mi = 0; mi < 2; ++mi)
            #pragma unroll
            for (int ni = 0; ni < 2; ++ni)
                acc[mi][ni] = __builtin_amdgcn_mfma_f32_16x16x32_bf16(
                    aF[mi], bF[ni], acc[mi][ni], 0, 0, 0);
    }

    // epilogue: D row = (lane>>4)*4 + reg, col = lane&15
    #pragma unroll
    for (int mi = 0; mi < 2; ++mi) {
        #pragma unroll
        for (int r = 0; r < 4; ++r) {
            int co = c0 + wm * 32 + mi * 16 + lkg * 4 + r;
            float s  = gg[co] * BN_RS;
            float bi = bb[co];
            size_t rowb = ((size_t)b * CO + co) * HW + p0 + wn * 32 + lrow;
            Y[rowb]      = silu_f(fmaf(acc[mi][0][r], s, bi));
            Y[rowb + 16] = silu_f(fmaf(acc[mi][1][r], s, bi));
        }
    }
}

// -------- one-time: transpose offset-conv weights to [tap][co(pad32)][ci] bf16 --------
__global__ __launch_bounds__(256) void k_woff_t(
    const float* __restrict__ Wo, unsigned short* __restrict__ Wt2)
{
    const int t = blockIdx.x;      // 0..8
    const int co = blockIdx.y;     // 0..31
    const int ci = threadIdx.x;    // 0..255
    float v = (co < 18) ? Wo[((size_t)co * 256 + ci) * 9 + t] : 0.0f;
    Wt2[((size_t)t * 32 + co) * 256 + ci] = f2bf(v);
}

// -------- 3x3 conv (256 -> 18) as implicit-GEMM MFMA, ci-split partials --------
// grid (y=64, b=4, q=4); block 256 = 4 waves; wave wn covers pos [wn*16,+16).
// Per q: 64 ci in 2 chunks of 32; per chunk stage hsT[3 rows][66 x][ci] bf16
// (k=ci contiguous -> B frag = 1 ds_read_b128); A frags direct from L2 (Wt2).
__global__ __launch_bounds__(256) void k_conv_off(
    const float* __restrict__ Hh, const unsigned short* __restrict__ Wt2,
    float* __restrict__ OffP)
{
    const int y = blockIdx.x;
    const int b = blockIdx.y;
    const int q = blockIdx.z;
    const int tid = threadIdx.x;
    const int wn = tid >> 6;
    const int lane = tid & 63;
    const int lrow = lane & 15, lkg = lane >> 4;

    __shared__ __align__(16) unsigned short hsT[3][66][40];  // [r][xx][ci], pad 40

    f32x4 acc[2];
    acc[0] = (f32x4){0.f, 0.f, 0.f, 0.f};
    acc[1] = (f32x4){0.f, 0.f, 0.f, 0.f};

    for (int cc = 0; cc < 2; ++cc) {
        const int ci0 = q * 64 + cc * 32;
        __syncthreads();
        // zero x halo (xx=0,65)
        if (tid < 192) {
            int r = tid / 64, which = (tid >> 5) & 1, ci = tid & 31;
            hsT[r][which ? 65 : 0][ci] = 0;
        }
        // stage 3 rows x 32 ci, transposed to [xx][ci] bf16
        #pragma unroll
        for (int it = 0; it < 6; ++it) {
            int i  = tid + it * 256;       // 0..1535
            int r  = i >> 9;
            int ci = (i >> 4) & 31;
            int x4 = (i & 15) << 2;
            int yy = y + r - 1;
            float4 v = make_float4(0.f, 0.f, 0.f, 0.f);
            if ((unsigned)yy < 64u)
                v = *(const float4*)&Hh[((size_t)(b * 256 + ci0 + ci) << 12) + yy * 64 + x4];
            hsT[r][1 + x4 + 0][ci] = f2bf(v.x);
            hsT[r][1 + x4 + 1][ci] = f2bf(v.y);
            hsT[r][1 + x4 + 2][ci] = f2bf(v.z);
            hsT[r][1 + x4 + 3][ci] = f2bf(v.w);
        }
        __syncthreads();

        #pragma unroll
        for (int t9 = 0; t9 < 9; ++t9) {
            const int ty = t9 / 3, tx = t9 % 3;
            short8 bF = *(const short8*)&hsT[ty][wn * 16 + lrow + tx][lkg * 8];
            #pragma unroll
            for (int mi = 0; mi < 2; ++mi) {
                short8 aF = *(const short8*)&Wt2[((size_t)t9 * 32 + mi * 16 + lrow) * 256
                                                 + ci0 + lkg * 8];
                acc[mi] = __builtin_amdgcn_mfma_f32_16x16x32_bf16(aF, bF, acc[mi], 0, 0, 0);
            }
        }
    }

    // D row(co) = lkg*4 + r, col(pos) = lrow
    #pragma unroll
    for (int mi = 0; mi < 2; ++mi) {
        #pragma unroll
        for (int r = 0; r < 4; ++r) {
            int co = mi * 16 + lkg * 4 + r;
            if (co < 18)
                OffP[(((size_t)q * 4 + b) * 18 + co) * HW + y * 64 + wn * 16 + lrow]
                    = acc[mi][r];
        }
    }
}

// -------- combine 4 ci-split partials + bias -> final offsets --------
__global__ __launch_bounds__(256) void k_off_combine(
    const float* __restrict__ OffP, const float* __restrict__ Bo,
    float* __restrict__ Off)
{
    const int bt = blockIdx.x;         // b*18 + t, 72 blocks
    const int b = bt / 18, t = bt - b * 18;
    const float bias = Bo[t];
    const size_t plane = ((size_t)b * 18 + t) * HW;
    #pragma unroll
    for (int it = 0; it < 4; ++it) {
        int p4 = (threadIdx.x + it * 256) * 4;
        float4 s = *(const float4*)&OffP[plane + p4];
        #pragma unroll
        for (int q = 1; q < 4; ++q) {
            float4 v = *(const float4*)&OffP[((size_t)q * 4 * 18) * HW + plane + p4];
            s.x += v.x; s.y += v.y; s.z += v.z; s.w += v.w;
        }
        s.x += bias; s.y += bias; s.z += bias; s.w += bias;
        *(float4*)&Off[plane + p4] = s;
    }
}

// ------------- deformable depthwise 3x3 + BN + SiLU + residual -------------
// XCD-pinned grid (idx%8 = q). Paired-corner gathers: one unaligned float2
// per (row,tap,channel) + cndmask selects.
__global__ __launch_bounds__(256, 4) void k_deform(
    const float* __restrict__ Hh, const float* __restrict__ Off,
    const float* __restrict__ Wd, const float* __restrict__ Gb,
    const float* __restrict__ Bb, float* __restrict__ H2)
{
    const int idx = blockIdx.x;
    const int bq  = idx & 31;
    const int y   = idx >> 5;
    const int b   = bq >> 3;
    const int q   = bq & 7;
    const int tid = threadIdx.x;
    const int x = tid & 63;
    const int g = tid >> 6;
    const int pos = y * 64 + x;

    __shared__ __align__(16) float wds[9 * 32];   // [k][lc]
    __shared__ float gbs[32], bbs[32];

    for (int i = tid; i < 288; i += 256) {
        int lc = i & 31, k = i >> 5;
        wds[i] = Wd[(q * 32 + lc) * 9 + k];
    }
    if (tid < 32) {
        gbs[tid] = Gb[q * 32 + tid] * BN_RS;
        bbs[tid] = Bb[q * 32 + tid];
    }
    __syncthreads();

    float acc[8];
    #pragma unroll
    for (int j = 0; j < 8; ++j) acc[j] = 0.f;

    const float* Ob  = Off + (size_t)b * 18 * HW + pos;
    const float* hb0 = Hh + ((size_t)(b * 256 + q * 32 + g * 8) << 12);

    for (int r = 0; r < 3; ++r) {
        int   rb0[3], rb1[3];
        int   o0[3], o1[3];
        float wy0[3], wy1[3], wx0[3], wx1[3];
        #pragma unroll
        for (int t = 0; t < 3; ++t) {
            int k = r * 3 + t;
            float dy = Ob[(size_t)(2 * k) * HW];
            float dx = Ob[(size_t)(2 * k + 1) * HW];
            float py = (float)(y + r - 1) + dy;
            float px = (float)(x + t - 1) + dx;
            float fy0 = floorf(py), fx0 = floorf(px);
            int y0 = (int)fy0, x0 = (int)fx0;
            float fy = py - fy0, fx = px - fx0;
            bool vy0 = ((unsigned)y0 < 64u), vy1 = ((unsigned)(y0 + 1) < 64u);
            bool vx0 = ((unsigned)x0 < 64u), vx1 = ((unsigned)(x0 + 1) < 64u);
            int cy0 = clamp64(y0), cy1 = clamp64(y0 + 1);
            int bx  = x0 < 0 ? 0 : (x0 > 62 ? 62 : x0);
            int d0 = x0 - bx;
            o0[t] = d0 < 0 ? 0 : d0;
            int d1 = d0 + 1;
            o1[t] = d1 > 1 ? 1 : d1;
            rb0[t] = cy0 * 64 + bx;
            rb1[t] = cy1 * 64 + bx;
            wy0[t] = vy0 ? (1.0f - fy) : 0.0f;
            wy1[t] = vy1 ? fy : 0.0f;
            wx0[t] = vx0 ? (1.0f - fx) : 0.0f;
            wx1[t] = vx1 ? fx : 0.0f;
        }
        #pragma unroll
        for (int j = 0; j < 8; ++j) {
            const float* hb = hb0 + ((size_t)j << 12);
            float a = acc[j];
            #pragma unroll
            for (int t = 0; t < 3; ++t) {
                f32x2u u0 = *(const f32x2u*)(hb + rb0[t]);
                f32x2u u1 = *(const f32x2u*)(hb + rb1[t]);
                float c00 = o0[t] ? u0.y : u0.x;
                float c01 = o1[t] ? u0.y : u0.x;
                float c10 = o0[t] ? u1.y : u1.x;
                float c11 = o1[t] ? u1.y : u1.x;
                float row0 = c00 * wx0[t] + c01 * wx1[t];
                float row1 = c10 * wx0[t] + c11 * wx1[t];
                float val  = row0 * wy0[t] + row1 * wy1[t];
                a = fmaf(val, wds[(r * 3 + t) * 32 + g * 8 + j], a);
            }
            acc[j] = a;
        }
    }

    #pragma unroll
    for (int j = 0; j < 8; ++j) {
        int lc = g * 8 + j;
        const float* hb = hb0 + ((size_t)j << 12);
        float t = fmaf(acc[j], gbs[lc], bbs[lc]);
        __builtin_nontemporal_store(silu_f(t) + hb[pos],
            &H2[((size_t)(b * 256 + q * 32 + lc) << 12) + pos]);
    }
}

// ---------------- SE: global mean over HxW ----------------
__global__ __launch_bounds__(256) void k_se_reduce(
    const float* __restrict__ Y, float* __restrict__ sb)
{
    const int bc = blockIdx.x;
    const float4* p = (const float4*)(Y + (size_t)bc * HW);
    int tid = threadIdx.x;
    float s = 0.f;
    #pragma unroll
    for (int it = 0; it < 4; ++it) {
        float4 v = p[tid + it * 256];
        s += v.x + v.y + v.z + v.w;
    }
    #pragma unroll
    for (int o = 32; o > 0; o >>= 1) s += __shfl_down(s, o);
    __shared__ float red[4];
    if ((tid & 63) == 0) red[tid >> 6] = s;
    __syncthreads();
    if (tid == 0) sb[bc] = (red[0] + red[1] + red[2] + red[3]) * (1.0f / 4096.0f);
}

// ---------------- SE: fc1(silu) + fc2(sigmoid) ----------------
__global__ __launch_bounds__(256) void k_se_fc(
    const float* __restrict__ sb, const float* __restrict__ wf1,
    const float* __restrict__ bf1, const float* __restrict__ wf2,
    const float* __restrict__ bf2, float* __restrict__ s2)
{
    const int b = blockIdx.x;
    const int t = threadIdx.x;
    __shared__ float sv[512];
    __shared__ float s1[32];
    sv[t]       = sb[b * 512 + t];
    sv[t + 256] = sb[b * 512 + t + 256];
    __syncthreads();
    if (t < 32) {
        float a = bf1[t];
        const float* w = wf1 + t * 512;
        for (int i = 0; i < 512; ++i) a = fmaf(w[i], sv[i], a);
        s1[t] = silu_f(a);
    }
    __syncthreads();
    #pragma unroll
    for (int it = 0; it < 2; ++it) {
        int co = t + it * 256;
        float a = bf2[co];
        const float* w = wf2 + co * 32;
        #pragma unroll
        for (int i = 0; i < 32; ++i) a = fmaf(w[i], s1[i], a);
        s2[b * 512 + co] = 1.0f / (1.0f + __expf(-a));
    }
}

// ---------------- final: out *= s ----------------
__global__ __launch_bounds__(256) void k_se_scale(
    float* __restrict__ Y, const float* __restrict__ s2)
{
    size_t i = (size_t)blockIdx.x * 256 + threadIdx.x;
    int bc = (int)(i >> 10);
    float sc = s2[bc];
    float4 v = ((float4*)Y)[i];
    v.x *= sc; v.y *= sc; v.z *= sc; v.w *= sc;
    ((float4*)Y)[i] = v;
}

extern "C" void kernel_launch(void* const* d_in, const int* in_sizes, int n_in,
                              void* d_out, int out_size, void* d_ws, size_t ws_size,
                              hipStream_t stream)
{
    const float* x   = (const float*)d_in[0];
    const float* w1  = (const float*)d_in[1];
    const float* g1  = (const float*)d_in[2];
    const float* b1  = (const float*)d_in[3];
    const float* wof = (const float*)d_in[4];
    const float* bof = (const float*)d_in[5];
    const float* wdw = (const float*)d_in[6];
    const float* gb  = (const float*)d_in[7];
    const float* bbv = (const float*)d_in[8];
    const float* w2  = (const float*)d_in[9];
    const float* g2  = (const float*)d_in[10];
    const float* b2  = (const float*)d_in[11];
    const float* wf1 = (const float*)d_in[12];
    const float* bf1 = (const float*)d_in[13];
    const float* wf2 = (const float*)d_in[14];
    const float* bf2 = (const float*)d_in[15];
    float* out = (float*)d_out;

    const size_t n_h    = 4ull * 256 * HW;        // 4,194,304
    const size_t n_offp = 4ull * 4 * 18 * HW;     // 1,179,648
    const size_t n_off  = 4ull * 18 * HW;         //   294,912
    const size_t n_wt2  = 9 * 32 * 256 / 2;       // 36,864 floats (bf16 x 73728)
    float* ws = (float*)d_ws;
    float *h, *offp, *offc, *h2, *sb, *s2, *wt2f;
    size_t need = (2 * n_h + n_offp + n_off + 2048 + 2048 + n_wt2 + 1024) * sizeof(float);
    if (ws_size >= need) {
        h = ws; offp = h + n_h; offc = offp + n_offp; h2 = offc + n_off;
        sb = h2 + n_h; s2 = sb + 2048; wt2f = s2 + 2048;
    } else {
        h = out;  // dead before conv2 writes out
        offp = ws; offc = offp + n_offp; h2 = offc + n_off;
        sb = h2 + n_h; s2 = sb + 2048; wt2f = s2 + 2048;
    }
    unsigned short* wt2 = (unsigned short*)wt2f;

    k_conv1x1_mfma<256, 512><<<dim3(64, 4, 4), 256, 0, stream>>>(x, w1, g1, b1, h);
    k_woff_t<<<dim3(9, 32), 256, 0, stream>>>(wof, wt2);
    k_conv_off<<<dim3(64, 4, 4), 256, 0, stream>>>(h, wt2, offp);
    k_off_combine<<<72, 256, 0, stream>>>(offp, bof, offc);
    k_deform<<<2048, 256, 0, stream>>>(h, offc, wdw, gb, bbv, h2);
    k_conv1x1_mfma<512, 256><<<dim3(64, 8, 4), 256, 0, stream>>>(h2, w2, g2, b2, out);
    k_se_reduce<<<2048, 256, 0, stream>>>(out, sb);
    k_se_fc<<<4, 256, 0, stream>>>(sb, wf1, bf1, wf2, bf2, s2);
    k_se_scale<<<8192, 256, 0, stream>>>(out, s2);
}